// Round 13
// baseline (72.778 us; speedup 1.0000x reference)
//
#include <hip/hip_runtime.h>
#include <hip/hip_bf16.h>

// FAVOR+ bidirectional linear attention, N=262144, D=64, fp32 in/out.
// Pass 1 (barrier-free loop, 3 blocks/CU): K/V projections (bf16 MFMA); kv
//   accumulated per-wave in registers — projection C-layout feeds the kv MFMA
//   directly via zero-padded k (k=lg*8+r on both operands => contraction over
//   the wave's 16 rows). No LDS/barriers in the loop; wave partials merged
//   once at the end through a 16KB LDS overlay of the dead weight-frag area.
// ReduceA (68 blocks, coalesced): kvPart row-slices -> l2kv[64][4112] (padded).
// ReduceB (5 blocks): -> kvFin[4096], ksFin[64].
// Pass 2 (zero LDS/barriers in loop): swapped Q-proj qp^T = mfma(Wq, x);
//   out^T = mfma(kvA_pi, qp_repack); denom = per-lane dot + 2 shfl_xor.

#define NPTS 262144
#define TILES (NPTS / 64)      // 4096
#define GRID1 512
#define TPB1 (TILES / GRID1)   // 8
#define GRID2 512
#define TPB2 (TILES / GRID2)   // 8
#define L2STRIDE 4112          // 4096 + 16 pad: breaks 16KB channel camping
#define EPS 1e-3f

typedef __attribute__((ext_vector_type(8))) short short8;   // 8 x bf16 (4 VGPRs)
typedef __attribute__((ext_vector_type(4))) float f32x4;

__device__ __forceinline__ unsigned short f2bf(float f) {
    unsigned u = __builtin_bit_cast(unsigned, f);
    u += 0x7FFFu + ((u >> 16) & 1u);           // round-to-nearest-even
    return (unsigned short)(u >> 16);
}

__device__ __forceinline__ short8 cvt8(float4 p0, float4 p1) {
    short8 a;
    a[0] = (short)f2bf(p0.x); a[1] = (short)f2bf(p0.y); a[2] = (short)f2bf(p0.z); a[3] = (short)f2bf(p0.w);
    a[4] = (short)f2bf(p1.x); a[5] = (short)f2bf(p1.y); a[6] = (short)f2bf(p1.z); a[7] = (short)f2bf(p1.w);
    return a;
}

// coalesced stage of a 64x64 f32 matrix -> LDS bf16 [64][72]
__device__ __forceinline__ void stage_mat(const float* __restrict__ W,
                                          unsigned short (*dst)[72], int srow, int sc0) {
    const float* p = W + srow * 64 + sc0;
    float4 f0 = ((const float4*)p)[0];
    float4 f1 = ((const float4*)p)[1];
    float4 f2 = ((const float4*)p)[2];
    float4 f3 = ((const float4*)p)[3];
    float ff[16] = {f0.x, f0.y, f0.z, f0.w, f1.x, f1.y, f1.z, f1.w,
                    f2.x, f2.y, f2.z, f2.w, f3.x, f3.y, f3.z, f3.w};
    unsigned hh[8];
#pragma unroll
    for (int e = 0; e < 8; ++e)
        hh[e] = (unsigned)f2bf(ff[2 * e]) | ((unsigned)f2bf(ff[2 * e + 1]) << 16);
    uint4 u0 = {hh[0], hh[1], hh[2], hh[3]};
    uint4 u1 = {hh[4], hh[5], hh[6], hh[7]};
    *(uint4*)&dst[srow][sc0] = u0;
    *(uint4*)&dst[srow][sc0 + 8] = u1;
}

__global__ __launch_bounds__(256, 3) void pass1_kernel(
    const float* __restrict__ x,
    const float* __restrict__ Wk, const float* __restrict__ bk,
    const float* __restrict__ Wv, const float* __restrict__ bv,
    float* __restrict__ kvPart, float* __restrict__ ksPart)
{
    __shared__ unsigned short stageS[64][72];    // startup W staging (9216 B)
    __shared__ unsigned short wF[16][64][8];     // [kv*8 + j*2+kk][lane][e] (16384 B)
    float* red = (float*)&wF[0][0][0];           // end-merge overlay (4096 f32)

    const int tid = threadIdx.x;
    const int w = tid >> 6, l = tid & 63, l15 = l & 15, lg = l >> 4;
    const int srow = tid >> 2, sc0 = (tid & 3) * 16;

    // ---- startup: coalesced W staging -> LDS bf16 -> frag build ----
    {
        const float* Ws[2] = {Wk, Wv};
#pragma unroll
        for (int m = 0; m < 2; ++m) {
            stage_mat(Ws[m], stageS, srow, sc0);
            __syncthreads();
            // wave w builds frag j=w: wF[m*8+j*2+kk][lane][e] = W[kk*32+lg*8+e][j*16+l15]
#pragma unroll
            for (int kk = 0; kk < 2; ++kk) {
                short8 t;
#pragma unroll
                for (int e = 0; e < 8; ++e)
                    t[e] = (short)stageS[kk * 32 + lg * 8 + e][w * 16 + l15];
                *(short8*)&wF[m * 8 + w * 2 + kk][l][0] = t;
            }
            __syncthreads();
        }
    }
    float bkl[4], bvl[4];
#pragma unroll
    for (int j = 0; j < 4; ++j) { bkl[j] = bk[j * 16 + l15]; bvl[j] = bv[j * 16 + l15]; }

    f32x4 akv[4][4];    // [jm][jd] reg r -> kv[jm*16+lg*4+r][jd*16+l15] (wave partial)
#pragma unroll
    for (int jm = 0; jm < 4; ++jm)
#pragma unroll
        for (int jd = 0; jd < 4; ++jd) akv[jm][jd] = (f32x4){0.f, 0.f, 0.f, 0.f};
    float ks[4] = {0.f, 0.f, 0.f, 0.f};

    const int t0 = blockIdx.x * TPB1;
    const float* xbase = x + ((size_t)t0 * 64 + w * 16 + l15) * 64 + lg * 8;
    float4 c0 = *(const float4*)(xbase + 0);
    float4 c1 = *(const float4*)(xbase + 4);
    float4 c2 = *(const float4*)(xbase + 32);
    float4 c3 = *(const float4*)(xbase + 36);

    for (int t = 0; t < TPB1; ++t) {
        // prefetch next tile (safe re-read of current on last iter)
        const float* xn = xbase + (size_t)((t + 1 < TPB1) ? (t + 1) : t) * 4096;
        float4 n0 = *(const float4*)(xn + 0);
        float4 n1 = *(const float4*)(xn + 4);
        float4 n2 = *(const float4*)(xn + 32);
        float4 n3 = *(const float4*)(xn + 36);

        short8 a0 = cvt8(c0, c1);
        short8 a1 = cvt8(c2, c3);

        short8 kpf[4], vf[4];   // zero-padded kv-MFMA operands (elements 4..7 = 0)
#pragma unroll
        for (int j = 0; j < 4; ++j) {
            short8 bk0 = *(const short8*)&wF[0 + j * 2 + 0][l][0];
            short8 bk1 = *(const short8*)&wF[0 + j * 2 + 1][l][0];
            short8 bv0 = *(const short8*)&wF[8 + j * 2 + 0][l][0];
            short8 bv1 = *(const short8*)&wF[8 + j * 2 + 1][l][0];
            f32x4 z = (f32x4){0.f, 0.f, 0.f, 0.f};
            f32x4 ak = __builtin_amdgcn_mfma_f32_16x16x32_bf16(a0, bk0, z, 0, 0, 0);
            ak = __builtin_amdgcn_mfma_f32_16x16x32_bf16(a1, bk1, ak, 0, 0, 0);
            f32x4 av = __builtin_amdgcn_mfma_f32_16x16x32_bf16(a0, bv0, z, 0, 0, 0);
            av = __builtin_amdgcn_mfma_f32_16x16x32_bf16(a1, bv1, av, 0, 0, 0);
            short8 kc = (short8){0, 0, 0, 0, 0, 0, 0, 0};
            short8 vc = (short8){0, 0, 0, 0, 0, 0, 0, 0};
#pragma unroll
            for (int r = 0; r < 4; ++r) {
                float kp = fmaxf(ak[r] + bkl[j], 0.f) + EPS;
                ks[j] += kp;
                kc[r] = (short)f2bf(kp);
                vc[r] = (short)f2bf(av[r] + bvl[j]);
            }
            kpf[j] = kc; vf[j] = vc;
        }
        // kv[m][d] += kp^T v over the wave's 16 rows: k = lg*8 + r on BOTH
        // operands (A[m=l15][k], B[k][d=l15]); zero k-slots contribute 0.
#pragma unroll
        for (int jm = 0; jm < 4; ++jm)
#pragma unroll
            for (int jd = 0; jd < 4; ++jd)
                akv[jm][jd] = __builtin_amdgcn_mfma_f32_16x16x32_bf16(kpf[jm], vf[jd], akv[jm][jd], 0, 0, 0);

        c0 = n0; c1 = n1; c2 = n2; c3 = n3;
    }

    // ---- end merge: serialize wave partials through 16KB red overlay ----
#define KV_IDX(jm, jd, r) ((size_t)((jm) * 16 + lg * 4 + (r)) * 64 + (jd) * 16 + l15)
    __syncthreads();   // all waves done reading wF frags
    if (w == 1) {
#pragma unroll
        for (int jm = 0; jm < 4; ++jm)
#pragma unroll
            for (int jd = 0; jd < 4; ++jd)
#pragma unroll
                for (int r = 0; r < 4; ++r) red[KV_IDX(jm, jd, r)] = akv[jm][jd][r];
    }
    __syncthreads();
    if (w == 0) {
#pragma unroll
        for (int jm = 0; jm < 4; ++jm)
#pragma unroll
            for (int jd = 0; jd < 4; ++jd)
#pragma unroll
                for (int r = 0; r < 4; ++r) akv[jm][jd][r] += red[KV_IDX(jm, jd, r)];
    }
    __syncthreads();
    if (w == 3) {
#pragma unroll
        for (int jm = 0; jm < 4; ++jm)
#pragma unroll
            for (int jd = 0; jd < 4; ++jd)
#pragma unroll
                for (int r = 0; r < 4; ++r) red[KV_IDX(jm, jd, r)] = akv[jm][jd][r];
    }
    __syncthreads();
    if (w == 2) {
#pragma unroll
        for (int jm = 0; jm < 4; ++jm)
#pragma unroll
            for (int jd = 0; jd < 4; ++jd)
#pragma unroll
                for (int r = 0; r < 4; ++r) akv[jm][jd][r] += red[KV_IDX(jm, jd, r)];
    }
    __syncthreads();
    if (w == 2) {
#pragma unroll
        for (int jm = 0; jm < 4; ++jm)
#pragma unroll
            for (int jd = 0; jd < 4; ++jd)
#pragma unroll
                for (int r = 0; r < 4; ++r) red[KV_IDX(jm, jd, r)] = akv[jm][jd][r];
    }
    __syncthreads();
    if (w == 0) {
        float* kvs = kvPart + (size_t)blockIdx.x * 4096;
#pragma unroll
        for (int jm = 0; jm < 4; ++jm)
#pragma unroll
            for (int jd = 0; jd < 4; ++jd)
#pragma unroll
                for (int r = 0; r < 4; ++r)
                    kvs[KV_IDX(jm, jd, r)] = akv[jm][jd][r] + red[KV_IDX(jm, jd, r)];
    }
#undef KV_IDX
    // ksum partial per (block, wave): reduce over lg within wave
#pragma unroll
    for (int j = 0; j < 4; ++j) {
        float s = ks[j];
        s += __shfl_xor(s, 16, 64);
        s += __shfl_xor(s, 32, 64);
        if (lg == 0) ksPart[(size_t)blockIdx.x * 256 + w * 64 + j * 16 + l15] = s;
    }
}

// 68 blocks: b<64 -> kv slice b (rows b*8..b*8+7, coalesced) -> l2kv[b][4096+pad]
//            b>=64 -> ks slice (128 block-rows each) -> l2ks[b-64][256]
__global__ __launch_bounds__(256, 4) void reduceA_kernel(
    const float* __restrict__ kvPart, const float* __restrict__ ksPart,
    float* __restrict__ l2kv, float* __restrict__ l2ks)
{
    const int b = blockIdx.x, t = threadIdx.x;
    if (b < 64) {
        f32x4 acc[4];
#pragma unroll
        for (int si = 0; si < 4; ++si) acc[si] = (f32x4){0.f, 0.f, 0.f, 0.f};
        const float* base = kvPart + (size_t)b * 8 * 4096;
#pragma unroll
        for (int r = 0; r < 8; ++r)
#pragma unroll
            for (int si = 0; si < 4; ++si)
                acc[si] += *(const f32x4*)(base + (size_t)r * 4096 + si * 1024 + t * 4);
#pragma unroll
        for (int si = 0; si < 4; ++si)
            *(f32x4*)(l2kv + (size_t)b * L2STRIDE + si * 1024 + t * 4) = acc[si];
    } else {
        const int i = b - 64;
        float acc = 0.f;
        const float* p = ksPart + (size_t)i * 128 * 256 + t;
#pragma unroll 8
        for (int r = 0; r < 128; ++r) acc += p[(size_t)r * 256];
        l2ks[i * 256 + t] = acc;
    }
}

// 5 blocks: b<4 -> kv col-group (coalesced 4KB segments over padded stride);
//           b==4 -> ksum[64]
__global__ __launch_bounds__(256, 4) void reduceB_kernel(
    const float* __restrict__ l2kv, const float* __restrict__ l2ks,
    float* __restrict__ kvFin, float* __restrict__ ksFin)
{
    const int b = blockIdx.x, t = threadIdx.x;
    if (b < 4) {
        f32x4 acc = (f32x4){0.f, 0.f, 0.f, 0.f};
        const float* p = l2kv + b * 1024 + t * 4;
#pragma unroll 8
        for (int s = 0; s < 64; ++s) acc += *(const f32x4*)(p + (size_t)s * L2STRIDE);
        *(f32x4*)(kvFin + b * 1024 + t * 4) = acc;
    } else if (t < 64) {
        float s = 0.f;
#pragma unroll
        for (int i = 0; i < 16; ++i) s += l2ks[i * 64 + t];
        ksFin[t] = s;
    }
}

__global__ __launch_bounds__(256, 2) void pass2_kernel(
    const float* __restrict__ x, const float* __restrict__ Wq, const float* __restrict__ bq,
    const float* __restrict__ kvFin, const float* __restrict__ ksFin,
    float* __restrict__ out)
{
    __shared__ unsigned short stageS[64][72];   // startup staging (Wq, then kv)
    __shared__ unsigned short wqF[8][64][8];    // Wq frags (A-role in swapped proj)

    const int tid = threadIdx.x;
    const int w = tid >> 6, l = tid & 63, l15 = l & 15, lg = l >> 4;
    const int srow = tid >> 2, sc0 = (tid & 3) * 16;

    stage_mat(Wq, stageS, srow, sc0);
    __syncthreads();
    {
#pragma unroll
        for (int kk = 0; kk < 2; ++kk) {
            short8 t;
#pragma unroll
            for (int e = 0; e < 8; ++e)
                t[e] = (short)stageS[kk * 32 + lg * 8 + e][w * 16 + l15];
            *(short8*)&wqF[w * 2 + kk][l][0] = t;
        }
    }
    __syncthreads();
    stage_mat(kvFin, stageS, srow, sc0);
    __syncthreads();
    // kv A'-frags with permuted contraction pi(lg,e,kk) = (kk*2+(e>>2))*16 + lg*4 + (e&3)
    short8 kvA[4][2];
#pragma unroll
    for (int dj = 0; dj < 4; ++dj)
#pragma unroll
        for (int kk = 0; kk < 2; ++kk) {
            short8 t;
#pragma unroll
            for (int e = 0; e < 8; ++e) {
                int m = (kk * 2 + (e >> 2)) * 16 + lg * 4 + (e & 3);
                t[e] = (short)stageS[m][dj * 16 + l15];
            }
            kvA[dj][kk] = t;
        }
    // per-lane bias / ksum for m = jm*16 + lg*4 + r
    float bql2[4][4], ksl2[4][4];
#pragma unroll
    for (int jm = 0; jm < 4; ++jm)
#pragma unroll
        for (int r = 0; r < 4; ++r) {
            bql2[jm][r] = bq[jm * 16 + lg * 4 + r];
            ksl2[jm][r] = ksFin[jm * 16 + lg * 4 + r];
        }

    const int t0 = blockIdx.x * TPB2;
    const float* xbase = x + ((size_t)t0 * 64 + w * 16 + l15) * 64 + lg * 8;
    float4 c0 = *(const float4*)(xbase + 0);
    float4 c1 = *(const float4*)(xbase + 4);
    float4 c2 = *(const float4*)(xbase + 32);
    float4 c3 = *(const float4*)(xbase + 36);

    for (int t = 0; t < TPB2; ++t) {
        const float* xn = xbase + (size_t)((t + 1 < TPB2) ? (t + 1) : t) * 4096;
        float4 n0 = *(const float4*)(xn + 0);
        float4 n1 = *(const float4*)(xn + 4);
        float4 n2 = *(const float4*)(xn + 32);
        float4 n3 = *(const float4*)(xn + 36);

        short8 a0 = cvt8(c0, c1);
        short8 a1 = cvt8(c2, c3);

        // swapped Q projection: lane holds qp[n=w*16+l15][m=jm*16+lg*4+r]
        const f32x4 z = (f32x4){0.f, 0.f, 0.f, 0.f};
        float dp = 0.f;
        short8 qb0, qb1;
#pragma unroll
        for (int jm = 0; jm < 4; ++jm) {
            short8 wq0 = *(const short8*)&wqF[jm * 2 + 0][l][0];
            short8 wq1 = *(const short8*)&wqF[jm * 2 + 1][l][0];
            f32x4 aq = __builtin_amdgcn_mfma_f32_16x16x32_bf16(wq0, a0, z, 0, 0, 0);
            aq = __builtin_amdgcn_mfma_f32_16x16x32_bf16(wq1, a1, aq, 0, 0, 0);
#pragma unroll
            for (int r = 0; r < 4; ++r) {
                float qv = fmaxf(aq[r] + bql2[jm][r], 0.f) + EPS;
                dp += qv * ksl2[jm][r];
                unsigned short h = f2bf(qv);
                if (jm < 2) qb0[(jm & 1) * 4 + r] = (short)h;
                else        qb1[(jm & 1) * 4 + r] = (short)h;
            }
        }
        dp += __shfl_xor(dp, 16, 64);
        dp += __shfl_xor(dp, 32, 64);
        const float inv = __builtin_amdgcn_rcpf(dp);

        const size_t nrow = (size_t)(t0 + t) * 64 + w * 16 + l15;
#pragma unroll
        for (int dj = 0; dj < 4; ++dj) {
            f32x4 nm = __builtin_amdgcn_mfma_f32_16x16x32_bf16(kvA[dj][0], qb0, z, 0, 0, 0);
            nm = __builtin_amdgcn_mfma_f32_16x16x32_bf16(kvA[dj][1], qb1, nm, 0, 0, 0);
            f32x4 o4 = {nm[0] * inv, nm[1] * inv, nm[2] * inv, nm[3] * inv};
            *(f32x4*)(out + nrow * 64 + dj * 16 + lg * 4) = o4;
        }
        c0 = n0; c1 = n1; c2 = n2; c3 = n3;
    }
}

extern "C" void kernel_launch(void* const* d_in, const int* in_sizes, int n_in,
                              void* d_out, int out_size, void* d_ws, size_t ws_size,
                              hipStream_t stream)
{
    const float* x  = (const float*)d_in[0];
    const float* Wq = (const float*)d_in[1];
    const float* bq = (const float*)d_in[2];
    const float* Wk = (const float*)d_in[3];
    const float* bk = (const float*)d_in[4];
    const float* Wv = (const float*)d_in[5];
    const float* bv = (const float*)d_in[6];
    float* out = (float*)d_out;

    float* kvPart = (float*)d_ws;                              // [512][4096] f32
    float* ksPart = kvPart + (size_t)GRID1 * 4096;             // [512][256] f32
    float* l2kv   = ksPart + (size_t)GRID1 * 256;              // [64][4112] f32
    float* l2ks   = l2kv + (size_t)64 * L2STRIDE;              // [4][256] f32
    float* kvFin  = l2ks + 4 * 256;                            // [4096] f32
    float* ksFin  = kvFin + 4096;                              // [64] f32

    hipLaunchKernelGGL(pass1_kernel, dim3(GRID1), dim3(256), 0, stream,
                       x, Wk, bk, Wv, bv, kvPart, ksPart);
    hipLaunchKernelGGL(reduceA_kernel, dim3(68), dim3(256), 0, stream,
                       kvPart, ksPart, l2kv, l2ks);
    hipLaunchKernelGGL(reduceB_kernel, dim3(5), dim3(256), 0, stream,
                       l2kv, l2ks, kvFin, ksFin);
    hipLaunchKernelGGL(pass2_kernel, dim3(GRID2), dim3(256), 0, stream,
                       x, Wq, bq, kvFin, ksFin, out);
}

// Round 14
// 60.309 us; speedup vs baseline: 1.2068x; 1.2068x over previous
//
#include <hip/hip_runtime.h>
#include <hip/hip_bf16.h>

// FAVOR+ bidirectional linear attention, N=262144, D=64, fp32 in/out.
// CHAMPION STRUCTURE (R8, 55.7us) restored verbatim; only reduceA split finer.
// Pass 1 (512 blocks, (256,4)): K/V projections (bf16 MFMA) -> kv via
//   LDS-transpose MFMA accumulate -> per-block partial kv/ksum (plain stores).
// ReduceA (132 blocks, coalesced): 128 blocks x 4 kvPart rows -> l2kv[128][4112]
//   (padded stride de-camps channels); 4 blocks x 128 ksPart rows -> l2ks.
// ReduceB (5 blocks): 128 slices -> kvFin[4096]; l2ks -> ksFin[64].
// Pass 2 (512 blocks, (256,2), zero LDS/barriers in loop): swapped Q-proj
//   qp^T = mfma(Wq, x); out^T = mfma(kvA_pi, qp_repack); denom = per-lane
//   dot + 2 shfl_xor; float4 stores.

#define NPTS 262144
#define TILES (NPTS / 64)      // 4096
#define GRID1 512
#define TPB1 (TILES / GRID1)   // 8
#define GRID2 512
#define TPB2 (TILES / GRID2)   // 8
#define L2STRIDE 4112          // 4096 + 16 pad: breaks 16KB channel camping
#define EPS 1e-3f

typedef __attribute__((ext_vector_type(8))) short short8;   // 8 x bf16 (4 VGPRs)
typedef __attribute__((ext_vector_type(4))) float f32x4;

__device__ __forceinline__ unsigned short f2bf(float f) {
    unsigned u = __builtin_bit_cast(unsigned, f);
    u += 0x7FFFu + ((u >> 16) & 1u);           // round-to-nearest-even
    return (unsigned short)(u >> 16);
}

__device__ __forceinline__ short8 cvt8(float4 p0, float4 p1) {
    short8 a;
    a[0] = (short)f2bf(p0.x); a[1] = (short)f2bf(p0.y); a[2] = (short)f2bf(p0.z); a[3] = (short)f2bf(p0.w);
    a[4] = (short)f2bf(p1.x); a[5] = (short)f2bf(p1.y); a[6] = (short)f2bf(p1.z); a[7] = (short)f2bf(p1.w);
    return a;
}

// barrier that drains LDS ops only (keeps global prefetch loads in flight)
__device__ __forceinline__ void lds_barrier() {
    asm volatile("s_waitcnt lgkmcnt(0)" ::: "memory");
    __builtin_amdgcn_s_barrier();
}

// coalesced stage of a 64x64 f32 matrix -> LDS bf16 [64][72]
__device__ __forceinline__ void stage_mat(const float* __restrict__ W,
                                          unsigned short (*dst)[72], int srow, int sc0) {
    const float* p = W + srow * 64 + sc0;
    float4 f0 = ((const float4*)p)[0];
    float4 f1 = ((const float4*)p)[1];
    float4 f2 = ((const float4*)p)[2];
    float4 f3 = ((const float4*)p)[3];
    float ff[16] = {f0.x, f0.y, f0.z, f0.w, f1.x, f1.y, f1.z, f1.w,
                    f2.x, f2.y, f2.z, f2.w, f3.x, f3.y, f3.z, f3.w};
    unsigned hh[8];
#pragma unroll
    for (int e = 0; e < 8; ++e)
        hh[e] = (unsigned)f2bf(ff[2 * e]) | ((unsigned)f2bf(ff[2 * e + 1]) << 16);
    uint4 u0 = {hh[0], hh[1], hh[2], hh[3]};
    uint4 u1 = {hh[4], hh[5], hh[6], hh[7]};
    *(uint4*)&dst[srow][sc0] = u0;
    *(uint4*)&dst[srow][sc0 + 8] = u1;
}

__global__ __launch_bounds__(256, 4) void pass1_kernel(
    const float* __restrict__ x,
    const float* __restrict__ Wk, const float* __restrict__ bk,
    const float* __restrict__ Wv, const float* __restrict__ bv,
    float* __restrict__ kvPart, float* __restrict__ ksPart)
{
    __shared__ unsigned short kpT[64][72];       // kp transposed [m][n]; startup: W staging
    __shared__ unsigned short vT[64][72];        // v  transposed [d][n]
    __shared__ unsigned short wkF[8][64][8];     // B-frags: [j*2+kk][lane][e]
    __shared__ unsigned short wvF[8][64][8];

    const int tid = threadIdx.x;
    const int w = tid >> 6, l = tid & 63, l15 = l & 15, lg = l >> 4;
    const int srow = tid >> 2, sc0 = (tid & 3) * 16;

    // ---- startup: coalesced W staging -> LDS bf16 -> frag build ----
    {
        const float* Ws[2] = {Wk, Wv};
        unsigned short (*Fs[2])[64][8] = {wkF, wvF};
#pragma unroll
        for (int m = 0; m < 2; ++m) {
            stage_mat(Ws[m], kpT, srow, sc0);
            __syncthreads();
            // wave w builds frag j=w: F[j*2+kk][lane][e] = W[kk*32+lg*8+e][j*16+l15]
#pragma unroll
            for (int kk = 0; kk < 2; ++kk) {
                short8 t;
#pragma unroll
                for (int e = 0; e < 8; ++e)
                    t[e] = (short)kpT[kk * 32 + lg * 8 + e][w * 16 + l15];
                *(short8*)&Fs[m][w * 2 + kk][l][0] = t;
            }
            __syncthreads();
        }
    }
    float bkl[4], bvl[4];
#pragma unroll
    for (int j = 0; j < 4; ++j) { bkl[j] = bk[j * 16 + l15]; bvl[j] = bv[j * 16 + l15]; }

    f32x4 akv[4];
#pragma unroll
    for (int j = 0; j < 4; ++j) akv[j] = (f32x4){0.f, 0.f, 0.f, 0.f};
    float ks[4] = {0.f, 0.f, 0.f, 0.f};

    const int t0 = blockIdx.x * TPB1;
    const float* xbase = x + ((size_t)t0 * 64 + w * 16 + l15) * 64 + lg * 8;
    float4 c0 = *(const float4*)(xbase + 0);
    float4 c1 = *(const float4*)(xbase + 4);
    float4 c2 = *(const float4*)(xbase + 32);
    float4 c3 = *(const float4*)(xbase + 36);
    const int nbase = w * 16 + lg * 4;

    for (int t = 0; t < TPB1; ++t) {
        // prefetch next tile (safe re-read of current on last iter)
        const float* xn = xbase + (size_t)((t + 1 < TPB1) ? (t + 1) : t) * 4096;
        float4 n0 = *(const float4*)(xn + 0);
        float4 n1 = *(const float4*)(xn + 4);
        float4 n2 = *(const float4*)(xn + 32);
        float4 n3 = *(const float4*)(xn + 36);

        short8 a0 = cvt8(c0, c1);
        short8 a1 = cvt8(c2, c3);

#pragma unroll
        for (int j = 0; j < 4; ++j) {
            short8 bk0 = *(const short8*)&wkF[j * 2 + 0][l][0];
            short8 bk1 = *(const short8*)&wkF[j * 2 + 1][l][0];
            short8 bv0 = *(const short8*)&wvF[j * 2 + 0][l][0];
            short8 bv1 = *(const short8*)&wvF[j * 2 + 1][l][0];
            f32x4 z = (f32x4){0.f, 0.f, 0.f, 0.f};
            f32x4 ak = __builtin_amdgcn_mfma_f32_16x16x32_bf16(a0, bk0, z, 0, 0, 0);
            ak = __builtin_amdgcn_mfma_f32_16x16x32_bf16(a1, bk1, ak, 0, 0, 0);
            f32x4 av = __builtin_amdgcn_mfma_f32_16x16x32_bf16(a0, bv0, z, 0, 0, 0);
            av = __builtin_amdgcn_mfma_f32_16x16x32_bf16(a1, bv1, av, 0, 0, 0);
            unsigned short h[4], g[4];
#pragma unroll
            for (int r = 0; r < 4; ++r) {
                float kp = fmaxf(ak[r] + bkl[j], 0.f) + EPS;
                ks[j] += kp;
                h[r] = f2bf(kp);
                g[r] = f2bf(av[r] + bvl[j]);
            }
            uint2 hp = {(unsigned)h[0] | ((unsigned)h[1] << 16), (unsigned)h[2] | ((unsigned)h[3] << 16)};
            uint2 gp = {(unsigned)g[0] | ((unsigned)g[1] << 16), (unsigned)g[2] | ((unsigned)g[3] << 16)};
            *(uint2*)&kpT[j * 16 + l15][nbase] = hp;   // kpT[m][n]
            *(uint2*)&vT[j * 16 + l15][nbase] = gp;    // vT[d][n]
        }
        lds_barrier();
        // kv[m][d] += sum_n kp[n][m] * v[n][d]; wave w owns m in [w*16, w*16+16)
        short8 ka0 = *(const short8*)&kpT[w * 16 + l15][lg * 8];
        short8 ka1 = *(const short8*)&kpT[w * 16 + l15][32 + lg * 8];
#pragma unroll
        for (int j = 0; j < 4; ++j) {
            short8 vb0 = *(const short8*)&vT[j * 16 + l15][lg * 8];
            short8 vb1 = *(const short8*)&vT[j * 16 + l15][32 + lg * 8];
            akv[j] = __builtin_amdgcn_mfma_f32_16x16x32_bf16(ka0, vb0, akv[j], 0, 0, 0);
            akv[j] = __builtin_amdgcn_mfma_f32_16x16x32_bf16(ka1, vb1, akv[j], 0, 0, 0);
        }
        lds_barrier();
        c0 = n0; c1 = n1; c2 = n2; c3 = n3;
    }

    // per-block partial stores (plain, coalesced)
    float* kvs = kvPart + (size_t)blockIdx.x * 4096;
#pragma unroll
    for (int j = 0; j < 4; ++j)
#pragma unroll
        for (int r = 0; r < 4; ++r)
            kvs[(size_t)(w * 16 + lg * 4 + r) * 64 + j * 16 + l15] = akv[j][r];
#pragma unroll
    for (int j = 0; j < 4; ++j) {
        float s = ks[j];
        s += __shfl_xor(s, 16, 64);
        s += __shfl_xor(s, 32, 64);
        if (lg == 0) ksPart[(size_t)blockIdx.x * 256 + w * 64 + j * 16 + l15] = s;
    }
}

// 132 blocks: b<128 -> kv rows b*4..b*4+3 (coalesced) -> l2kv[b][4096+pad]
//             b>=128 -> ks rows (b-128)*128..+127 -> l2ks[b-128][256]
__global__ __launch_bounds__(256, 4) void reduceA_kernel(
    const float* __restrict__ kvPart, const float* __restrict__ ksPart,
    float* __restrict__ l2kv, float* __restrict__ l2ks)
{
    const int b = blockIdx.x, t = threadIdx.x;
    if (b < 128) {
        f32x4 acc[4];
#pragma unroll
        for (int si = 0; si < 4; ++si) acc[si] = (f32x4){0.f, 0.f, 0.f, 0.f};
        const float* base = kvPart + (size_t)b * 4 * 4096;
#pragma unroll
        for (int r = 0; r < 4; ++r)
#pragma unroll
            for (int si = 0; si < 4; ++si)
                acc[si] += *(const f32x4*)(base + (size_t)r * 4096 + si * 1024 + t * 4);
#pragma unroll
        for (int si = 0; si < 4; ++si)
            *(f32x4*)(l2kv + (size_t)b * L2STRIDE + si * 1024 + t * 4) = acc[si];
    } else {
        const int i = b - 128;
        float acc = 0.f;
        const float* p = ksPart + (size_t)i * 128 * 256 + t;
#pragma unroll 8
        for (int r = 0; r < 128; ++r) acc += p[(size_t)r * 256];
        l2ks[i * 256 + t] = acc;
    }
}

// 5 blocks: b<4 -> kv col-group (coalesced 4KB segments over padded stride,
//           128 slices); b==4 -> ksum[64]
__global__ __launch_bounds__(256, 4) void reduceB_kernel(
    const float* __restrict__ l2kv, const float* __restrict__ l2ks,
    float* __restrict__ kvFin, float* __restrict__ ksFin)
{
    const int b = blockIdx.x, t = threadIdx.x;
    if (b < 4) {
        f32x4 acc = (f32x4){0.f, 0.f, 0.f, 0.f};
        const float* p = l2kv + b * 1024 + t * 4;
#pragma unroll 8
        for (int s = 0; s < 128; ++s) acc += *(const f32x4*)(p + (size_t)s * L2STRIDE);
        *(f32x4*)(kvFin + b * 1024 + t * 4) = acc;
    } else if (t < 64) {
        float s = 0.f;
#pragma unroll
        for (int i = 0; i < 16; ++i) s += l2ks[i * 64 + t];
        ksFin[t] = s;
    }
}

__global__ __launch_bounds__(256, 2) void pass2_kernel(
    const float* __restrict__ x, const float* __restrict__ Wq, const float* __restrict__ bq,
    const float* __restrict__ kvFin, const float* __restrict__ ksFin,
    float* __restrict__ out)
{
    __shared__ unsigned short stageS[64][72];   // startup staging (Wq, then kv)
    __shared__ unsigned short wqF[8][64][8];    // Wq frags (A-role in swapped proj)

    const int tid = threadIdx.x;
    const int w = tid >> 6, l = tid & 63, l15 = l & 15, lg = l >> 4;
    const int srow = tid >> 2, sc0 = (tid & 3) * 16;

    stage_mat(Wq, stageS, srow, sc0);
    __syncthreads();
    {
#pragma unroll
        for (int kk = 0; kk < 2; ++kk) {
            short8 t;
#pragma unroll
            for (int e = 0; e < 8; ++e)
                t[e] = (short)stageS[kk * 32 + lg * 8 + e][w * 16 + l15];
            *(short8*)&wqF[w * 2 + kk][l][0] = t;
        }
    }
    __syncthreads();
    stage_mat(kvFin, stageS, srow, sc0);
    __syncthreads();
    // kv A'-frags with permuted contraction pi(lg,e,kk) = (kk*2+(e>>2))*16 + lg*4 + (e&3)
    short8 kvA[4][2];
#pragma unroll
    for (int dj = 0; dj < 4; ++dj)
#pragma unroll
        for (int kk = 0; kk < 2; ++kk) {
            short8 t;
#pragma unroll
            for (int e = 0; e < 8; ++e) {
                int m = (kk * 2 + (e >> 2)) * 16 + lg * 4 + (e & 3);
                t[e] = (short)stageS[m][dj * 16 + l15];
            }
            kvA[dj][kk] = t;
        }
    // per-lane bias / ksum for m = jm*16 + lg*4 + r
    float bql2[4][4], ksl2[4][4];
#pragma unroll
    for (int jm = 0; jm < 4; ++jm)
#pragma unroll
        for (int r = 0; r < 4; ++r) {
            bql2[jm][r] = bq[jm * 16 + lg * 4 + r];
            ksl2[jm][r] = ksFin[jm * 16 + lg * 4 + r];
        }

    const int t0 = blockIdx.x * TPB2;
    const float* xbase = x + ((size_t)t0 * 64 + w * 16 + l15) * 64 + lg * 8;
    float4 c0 = *(const float4*)(xbase + 0);
    float4 c1 = *(const float4*)(xbase + 4);
    float4 c2 = *(const float4*)(xbase + 32);
    float4 c3 = *(const float4*)(xbase + 36);

    for (int t = 0; t < TPB2; ++t) {
        const float* xn = xbase + (size_t)((t + 1 < TPB2) ? (t + 1) : t) * 4096;
        float4 n0 = *(const float4*)(xn + 0);
        float4 n1 = *(const float4*)(xn + 4);
        float4 n2 = *(const float4*)(xn + 32);
        float4 n3 = *(const float4*)(xn + 36);

        short8 a0 = cvt8(c0, c1);
        short8 a1 = cvt8(c2, c3);

        // swapped Q projection: lane holds qp[n=w*16+l15][m=jm*16+lg*4+r]
        const f32x4 z = (f32x4){0.f, 0.f, 0.f, 0.f};
        float dp = 0.f;
        short8 qb0, qb1;
#pragma unroll
        for (int jm = 0; jm < 4; ++jm) {
            short8 wq0 = *(const short8*)&wqF[jm * 2 + 0][l][0];
            short8 wq1 = *(const short8*)&wqF[jm * 2 + 1][l][0];
            f32x4 aq = __builtin_amdgcn_mfma_f32_16x16x32_bf16(wq0, a0, z, 0, 0, 0);
            aq = __builtin_amdgcn_mfma_f32_16x16x32_bf16(wq1, a1, aq, 0, 0, 0);
#pragma unroll
            for (int r = 0; r < 4; ++r) {
                float qv = fmaxf(aq[r] + bql2[jm][r], 0.f) + EPS;
                dp += qv * ksl2[jm][r];
                unsigned short h = f2bf(qv);
                if (jm < 2) qb0[(jm & 1) * 4 + r] = (short)h;
                else        qb1[(jm & 1) * 4 + r] = (short)h;
            }
        }
        dp += __shfl_xor(dp, 16, 64);
        dp += __shfl_xor(dp, 32, 64);
        const float inv = __builtin_amdgcn_rcpf(dp);

        const size_t nrow = (size_t)(t0 + t) * 64 + w * 16 + l15;
#pragma unroll
        for (int dj = 0; dj < 4; ++dj) {
            f32x4 nm = __builtin_amdgcn_mfma_f32_16x16x32_bf16(kvA[dj][0], qb0, z, 0, 0, 0);
            nm = __builtin_amdgcn_mfma_f32_16x16x32_bf16(kvA[dj][1], qb1, nm, 0, 0, 0);
            f32x4 o4 = {nm[0] * inv, nm[1] * inv, nm[2] * inv, nm[3] * inv};
            *(f32x4*)(out + nrow * 64 + dj * 16 + lg * 4) = o4;
        }
        c0 = n0; c1 = n1; c2 = n2; c3 = n3;
    }
}

extern "C" void kernel_launch(void* const* d_in, const int* in_sizes, int n_in,
                              void* d_out, int out_size, void* d_ws, size_t ws_size,
                              hipStream_t stream)
{
    const float* x  = (const float*)d_in[0];
    const float* Wq = (const float*)d_in[1];
    const float* bq = (const float*)d_in[2];
    const float* Wk = (const float*)d_in[3];
    const float* bk = (const float*)d_in[4];
    const float* Wv = (const float*)d_in[5];
    const float* bv = (const float*)d_in[6];
    float* out = (float*)d_out;

    float* kvPart = (float*)d_ws;                              // [512][4096] f32
    float* ksPart = kvPart + (size_t)GRID1 * 4096;             // [512][256] f32
    float* l2kv   = ksPart + (size_t)GRID1 * 256;              // [128][4112] f32
    float* l2ks   = l2kv + (size_t)128 * L2STRIDE;             // [4][256] f32
    float* kvFin  = l2ks + 4 * 256;                            // [4096] f32
    float* ksFin  = kvFin + 4096;                              // [64] f32

    hipLaunchKernelGGL(pass1_kernel, dim3(GRID1), dim3(256), 0, stream,
                       x, Wk, bk, Wv, bv, kvPart, ksPart);
    hipLaunchKernelGGL(reduceA_kernel, dim3(132), dim3(256), 0, stream,
                       kvPart, ksPart, l2kv, l2ks);
    hipLaunchKernelGGL(reduceB_kernel, dim3(5), dim3(256), 0, stream,
                       l2kv, l2ks, kvFin, ksFin);
    hipLaunchKernelGGL(pass2_kernel, dim3(GRID2), dim3(256), 0, stream,
                       x, Wq, bq, kvFin, ksFin, out);
}

// Round 15
// 54.328 us; speedup vs baseline: 1.3396x; 1.1101x over previous
//
#include <hip/hip_runtime.h>
#include <hip/hip_bf16.h>

// FAVOR+ bidirectional linear attention, N=262144, D=64, fp32 in/out.
// R8 champion structure; reduce chain collapsed to ONE kernel (atomic finish).
// Pass 1 (512 blocks, (256,4)): K/V projections (bf16 MFMA) -> kv via
//   LDS-transpose MFMA accumulate -> per-block partial kv/ksum (plain stores).
//   Block 0 additionally zero-inits kvFin/ksFin (stream-ordered before reduce).
// Reduce (20 blocks): 16 blocks x 32 kvPart rows (coalesced) -> atomicAdd into
//   kvFin (16 collisions/address); 4 blocks x 128 ksPart rows -> ksFin.
// Pass 2 (512 blocks, (256,2), zero LDS/barriers in loop): swapped Q-proj
//   qp^T = mfma(Wq, x); out^T = mfma(kvA_pi, qp_repack); denom = per-lane
//   dot + 2 shfl_xor; float4 stores.

#define NPTS 262144
#define TILES (NPTS / 64)      // 4096
#define GRID1 512
#define TPB1 (TILES / GRID1)   // 8
#define GRID2 512
#define TPB2 (TILES / GRID2)   // 8
#define EPS 1e-3f

typedef __attribute__((ext_vector_type(8))) short short8;   // 8 x bf16 (4 VGPRs)
typedef __attribute__((ext_vector_type(4))) float f32x4;

__device__ __forceinline__ unsigned short f2bf(float f) {
    unsigned u = __builtin_bit_cast(unsigned, f);
    u += 0x7FFFu + ((u >> 16) & 1u);           // round-to-nearest-even
    return (unsigned short)(u >> 16);
}

__device__ __forceinline__ short8 cvt8(float4 p0, float4 p1) {
    short8 a;
    a[0] = (short)f2bf(p0.x); a[1] = (short)f2bf(p0.y); a[2] = (short)f2bf(p0.z); a[3] = (short)f2bf(p0.w);
    a[4] = (short)f2bf(p1.x); a[5] = (short)f2bf(p1.y); a[6] = (short)f2bf(p1.z); a[7] = (short)f2bf(p1.w);
    return a;
}

// barrier that drains LDS ops only (keeps global prefetch loads in flight)
__device__ __forceinline__ void lds_barrier() {
    asm volatile("s_waitcnt lgkmcnt(0)" ::: "memory");
    __builtin_amdgcn_s_barrier();
}

// coalesced stage of a 64x64 f32 matrix -> LDS bf16 [64][72]
__device__ __forceinline__ void stage_mat(const float* __restrict__ W,
                                          unsigned short (*dst)[72], int srow, int sc0) {
    const float* p = W + srow * 64 + sc0;
    float4 f0 = ((const float4*)p)[0];
    float4 f1 = ((const float4*)p)[1];
    float4 f2 = ((const float4*)p)[2];
    float4 f3 = ((const float4*)p)[3];
    float ff[16] = {f0.x, f0.y, f0.z, f0.w, f1.x, f1.y, f1.z, f1.w,
                    f2.x, f2.y, f2.z, f2.w, f3.x, f3.y, f3.z, f3.w};
    unsigned hh[8];
#pragma unroll
    for (int e = 0; e < 8; ++e)
        hh[e] = (unsigned)f2bf(ff[2 * e]) | ((unsigned)f2bf(ff[2 * e + 1]) << 16);
    uint4 u0 = {hh[0], hh[1], hh[2], hh[3]};
    uint4 u1 = {hh[4], hh[5], hh[6], hh[7]};
    *(uint4*)&dst[srow][sc0] = u0;
    *(uint4*)&dst[srow][sc0 + 8] = u1;
}

__global__ __launch_bounds__(256, 4) void pass1_kernel(
    const float* __restrict__ x,
    const float* __restrict__ Wk, const float* __restrict__ bk,
    const float* __restrict__ Wv, const float* __restrict__ bv,
    float* __restrict__ kvPart, float* __restrict__ ksPart,
    float* __restrict__ kvFin, float* __restrict__ ksFin)
{
    __shared__ unsigned short kpT[64][72];       // kp transposed [m][n]; startup: W staging
    __shared__ unsigned short vT[64][72];        // v  transposed [d][n]
    __shared__ unsigned short wkF[8][64][8];     // B-frags: [j*2+kk][lane][e]
    __shared__ unsigned short wvF[8][64][8];

    const int tid = threadIdx.x;
    const int w = tid >> 6, l = tid & 63, l15 = l & 15, lg = l >> 4;
    const int srow = tid >> 2, sc0 = (tid & 3) * 16;

    // block 0 zero-inits the atomic-reduce targets (ws is poisoned 0xAA)
    if (blockIdx.x == 0) {
        const f32x4 z4 = (f32x4){0.f, 0.f, 0.f, 0.f};
#pragma unroll
        for (int i = 0; i < 4; ++i)
            *(f32x4*)(kvFin + tid * 16 + i * 4) = z4;
        if (tid < 64) ksFin[tid] = 0.f;
    }

    // ---- startup: coalesced W staging -> LDS bf16 -> frag build ----
    {
        const float* Ws[2] = {Wk, Wv};
        unsigned short (*Fs[2])[64][8] = {wkF, wvF};
#pragma unroll
        for (int m = 0; m < 2; ++m) {
            stage_mat(Ws[m], kpT, srow, sc0);
            __syncthreads();
            // wave w builds frag j=w: F[j*2+kk][lane][e] = W[kk*32+lg*8+e][j*16+l15]
#pragma unroll
            for (int kk = 0; kk < 2; ++kk) {
                short8 t;
#pragma unroll
                for (int e = 0; e < 8; ++e)
                    t[e] = (short)kpT[kk * 32 + lg * 8 + e][w * 16 + l15];
                *(short8*)&Fs[m][w * 2 + kk][l][0] = t;
            }
            __syncthreads();
        }
    }
    float bkl[4], bvl[4];
#pragma unroll
    for (int j = 0; j < 4; ++j) { bkl[j] = bk[j * 16 + l15]; bvl[j] = bv[j * 16 + l15]; }

    f32x4 akv[4];
#pragma unroll
    for (int j = 0; j < 4; ++j) akv[j] = (f32x4){0.f, 0.f, 0.f, 0.f};
    float ks[4] = {0.f, 0.f, 0.f, 0.f};

    const int t0 = blockIdx.x * TPB1;
    const float* xbase = x + ((size_t)t0 * 64 + w * 16 + l15) * 64 + lg * 8;
    float4 c0 = *(const float4*)(xbase + 0);
    float4 c1 = *(const float4*)(xbase + 4);
    float4 c2 = *(const float4*)(xbase + 32);
    float4 c3 = *(const float4*)(xbase + 36);
    const int nbase = w * 16 + lg * 4;

    for (int t = 0; t < TPB1; ++t) {
        // prefetch next tile (safe re-read of current on last iter)
        const float* xn = xbase + (size_t)((t + 1 < TPB1) ? (t + 1) : t) * 4096;
        float4 n0 = *(const float4*)(xn + 0);
        float4 n1 = *(const float4*)(xn + 4);
        float4 n2 = *(const float4*)(xn + 32);
        float4 n3 = *(const float4*)(xn + 36);

        short8 a0 = cvt8(c0, c1);
        short8 a1 = cvt8(c2, c3);

#pragma unroll
        for (int j = 0; j < 4; ++j) {
            short8 bk0 = *(const short8*)&wkF[j * 2 + 0][l][0];
            short8 bk1 = *(const short8*)&wkF[j * 2 + 1][l][0];
            short8 bv0 = *(const short8*)&wvF[j * 2 + 0][l][0];
            short8 bv1 = *(const short8*)&wvF[j * 2 + 1][l][0];
            f32x4 z = (f32x4){0.f, 0.f, 0.f, 0.f};
            f32x4 ak = __builtin_amdgcn_mfma_f32_16x16x32_bf16(a0, bk0, z, 0, 0, 0);
            ak = __builtin_amdgcn_mfma_f32_16x16x32_bf16(a1, bk1, ak, 0, 0, 0);
            f32x4 av = __builtin_amdgcn_mfma_f32_16x16x32_bf16(a0, bv0, z, 0, 0, 0);
            av = __builtin_amdgcn_mfma_f32_16x16x32_bf16(a1, bv1, av, 0, 0, 0);
            unsigned short h[4], g[4];
#pragma unroll
            for (int r = 0; r < 4; ++r) {
                float kp = fmaxf(ak[r] + bkl[j], 0.f) + EPS;
                ks[j] += kp;
                h[r] = f2bf(kp);
                g[r] = f2bf(av[r] + bvl[j]);
            }
            uint2 hp = {(unsigned)h[0] | ((unsigned)h[1] << 16), (unsigned)h[2] | ((unsigned)h[3] << 16)};
            uint2 gp = {(unsigned)g[0] | ((unsigned)g[1] << 16), (unsigned)g[2] | ((unsigned)g[3] << 16)};
            *(uint2*)&kpT[j * 16 + l15][nbase] = hp;   // kpT[m][n]
            *(uint2*)&vT[j * 16 + l15][nbase] = gp;    // vT[d][n]
        }
        lds_barrier();
        // kv[m][d] += sum_n kp[n][m] * v[n][d]; wave w owns m in [w*16, w*16+16)
        short8 ka0 = *(const short8*)&kpT[w * 16 + l15][lg * 8];
        short8 ka1 = *(const short8*)&kpT[w * 16 + l15][32 + lg * 8];
#pragma unroll
        for (int j = 0; j < 4; ++j) {
            short8 vb0 = *(const short8*)&vT[j * 16 + l15][lg * 8];
            short8 vb1 = *(const short8*)&vT[j * 16 + l15][32 + lg * 8];
            akv[j] = __builtin_amdgcn_mfma_f32_16x16x32_bf16(ka0, vb0, akv[j], 0, 0, 0);
            akv[j] = __builtin_amdgcn_mfma_f32_16x16x32_bf16(ka1, vb1, akv[j], 0, 0, 0);
        }
        lds_barrier();
        c0 = n0; c1 = n1; c2 = n2; c3 = n3;
    }

    // per-block partial stores (plain, coalesced)
    float* kvs = kvPart + (size_t)blockIdx.x * 4096;
#pragma unroll
    for (int j = 0; j < 4; ++j)
#pragma unroll
        for (int r = 0; r < 4; ++r)
            kvs[(size_t)(w * 16 + lg * 4 + r) * 64 + j * 16 + l15] = akv[j][r];
#pragma unroll
    for (int j = 0; j < 4; ++j) {
        float s = ks[j];
        s += __shfl_xor(s, 16, 64);
        s += __shfl_xor(s, 32, 64);
        if (lg == 0) ksPart[(size_t)blockIdx.x * 256 + w * 64 + j * 16 + l15] = s;
    }
}

// 20 blocks: b<16 -> sum kvPart rows b*32..b*32+31 (coalesced) -> atomicAdd
//            into kvFin; b>=16 -> sum ksPart rows (b-16)*128..+127 -> ksFin
__global__ __launch_bounds__(256, 4) void reduce_kernel(
    const float* __restrict__ kvPart, const float* __restrict__ ksPart,
    float* __restrict__ kvFin, float* __restrict__ ksFin)
{
    const int b = blockIdx.x, t = threadIdx.x;
    if (b < 16) {
        f32x4 acc[4];
#pragma unroll
        for (int si = 0; si < 4; ++si) acc[si] = (f32x4){0.f, 0.f, 0.f, 0.f};
        const float* base = kvPart + (size_t)b * 32 * 4096;
#pragma unroll 4
        for (int r = 0; r < 32; ++r)
#pragma unroll
            for (int si = 0; si < 4; ++si)
                acc[si] += *(const f32x4*)(base + (size_t)r * 4096 + si * 1024 + t * 4);
#pragma unroll
        for (int si = 0; si < 4; ++si)
#pragma unroll
            for (int e = 0; e < 4; ++e)
                unsafeAtomicAdd(&kvFin[si * 1024 + t * 4 + e], acc[si][e]);
    } else {
        const int i = b - 16;
        float acc = 0.f;
        const float* p = ksPart + (size_t)i * 128 * 256 + t;
#pragma unroll 8
        for (int r = 0; r < 128; ++r) acc += p[(size_t)r * 256];
        unsafeAtomicAdd(&ksFin[t & 63], acc);
    }
}

__global__ __launch_bounds__(256, 2) void pass2_kernel(
    const float* __restrict__ x, const float* __restrict__ Wq, const float* __restrict__ bq,
    const float* __restrict__ kvFin, const float* __restrict__ ksFin,
    float* __restrict__ out)
{
    __shared__ unsigned short stageS[64][72];   // startup staging (Wq, then kv)
    __shared__ unsigned short wqF[8][64][8];    // Wq frags (A-role in swapped proj)

    const int tid = threadIdx.x;
    const int w = tid >> 6, l = tid & 63, l15 = l & 15, lg = l >> 4;
    const int srow = tid >> 2, sc0 = (tid & 3) * 16;

    stage_mat(Wq, stageS, srow, sc0);
    __syncthreads();
    {
#pragma unroll
        for (int kk = 0; kk < 2; ++kk) {
            short8 t;
#pragma unroll
            for (int e = 0; e < 8; ++e)
                t[e] = (short)stageS[kk * 32 + lg * 8 + e][w * 16 + l15];
            *(short8*)&wqF[w * 2 + kk][l][0] = t;
        }
    }
    __syncthreads();
    stage_mat(kvFin, stageS, srow, sc0);
    __syncthreads();
    // kv A'-frags with permuted contraction pi(lg,e,kk) = (kk*2+(e>>2))*16 + lg*4 + (e&3)
    short8 kvA[4][2];
#pragma unroll
    for (int dj = 0; dj < 4; ++dj)
#pragma unroll
        for (int kk = 0; kk < 2; ++kk) {
            short8 t;
#pragma unroll
            for (int e = 0; e < 8; ++e) {
                int m = (kk * 2 + (e >> 2)) * 16 + lg * 4 + (e & 3);
                t[e] = (short)stageS[m][dj * 16 + l15];
            }
            kvA[dj][kk] = t;
        }
    // per-lane bias / ksum for m = jm*16 + lg*4 + r
    float bql2[4][4], ksl2[4][4];
#pragma unroll
    for (int jm = 0; jm < 4; ++jm)
#pragma unroll
        for (int r = 0; r < 4; ++r) {
            bql2[jm][r] = bq[jm * 16 + lg * 4 + r];
            ksl2[jm][r] = ksFin[jm * 16 + lg * 4 + r];
        }

    const int t0 = blockIdx.x * TPB2;
    const float* xbase = x + ((size_t)t0 * 64 + w * 16 + l15) * 64 + lg * 8;
    float4 c0 = *(const float4*)(xbase + 0);
    float4 c1 = *(const float4*)(xbase + 4);
    float4 c2 = *(const float4*)(xbase + 32);
    float4 c3 = *(const float4*)(xbase + 36);

    for (int t = 0; t < TPB2; ++t) {
        const float* xn = xbase + (size_t)((t + 1 < TPB2) ? (t + 1) : t) * 4096;
        float4 n0 = *(const float4*)(xn + 0);
        float4 n1 = *(const float4*)(xn + 4);
        float4 n2 = *(const float4*)(xn + 32);
        float4 n3 = *(const float4*)(xn + 36);

        short8 a0 = cvt8(c0, c1);
        short8 a1 = cvt8(c2, c3);

        // swapped Q projection: lane holds qp[n=w*16+l15][m=jm*16+lg*4+r]
        const f32x4 z = (f32x4){0.f, 0.f, 0.f, 0.f};
        float dp = 0.f;
        short8 qb0, qb1;
#pragma unroll
        for (int jm = 0; jm < 4; ++jm) {
            short8 wq0 = *(const short8*)&wqF[jm * 2 + 0][l][0];
            short8 wq1 = *(const short8*)&wqF[jm * 2 + 1][l][0];
            f32x4 aq = __builtin_amdgcn_mfma_f32_16x16x32_bf16(wq0, a0, z, 0, 0, 0);
            aq = __builtin_amdgcn_mfma_f32_16x16x32_bf16(wq1, a1, aq, 0, 0, 0);
#pragma unroll
            for (int r = 0; r < 4; ++r) {
                float qv = fmaxf(aq[r] + bql2[jm][r], 0.f) + EPS;
                dp += qv * ksl2[jm][r];
                unsigned short h = f2bf(qv);
                if (jm < 2) qb0[(jm & 1) * 4 + r] = (short)h;
                else        qb1[(jm & 1) * 4 + r] = (short)h;
            }
        }
        dp += __shfl_xor(dp, 16, 64);
        dp += __shfl_xor(dp, 32, 64);
        const float inv = __builtin_amdgcn_rcpf(dp);

        const size_t nrow = (size_t)(t0 + t) * 64 + w * 16 + l15;
#pragma unroll
        for (int dj = 0; dj < 4; ++dj) {
            f32x4 nm = __builtin_amdgcn_mfma_f32_16x16x32_bf16(kvA[dj][0], qb0, z, 0, 0, 0);
            nm = __builtin_amdgcn_mfma_f32_16x16x32_bf16(kvA[dj][1], qb1, nm, 0, 0, 0);
            f32x4 o4 = {nm[0] * inv, nm[1] * inv, nm[2] * inv, nm[3] * inv};
            *(f32x4*)(out + nrow * 64 + dj * 16 + lg * 4) = o4;
        }
        c0 = n0; c1 = n1; c2 = n2; c3 = n3;
    }
}

extern "C" void kernel_launch(void* const* d_in, const int* in_sizes, int n_in,
                              void* d_out, int out_size, void* d_ws, size_t ws_size,
                              hipStream_t stream)
{
    const float* x  = (const float*)d_in[0];
    const float* Wq = (const float*)d_in[1];
    const float* bq = (const float*)d_in[2];
    const float* Wk = (const float*)d_in[3];
    const float* bk = (const float*)d_in[4];
    const float* Wv = (const float*)d_in[5];
    const float* bv = (const float*)d_in[6];
    float* out = (float*)d_out;

    float* kvPart = (float*)d_ws;                              // [512][4096] f32
    float* ksPart = kvPart + (size_t)GRID1 * 4096;             // [512][256] f32
    float* kvFin  = ksPart + (size_t)GRID1 * 256;              // [4096] f32
    float* ksFin  = kvFin + 4096;                              // [64] f32

    hipLaunchKernelGGL(pass1_kernel, dim3(GRID1), dim3(256), 0, stream,
                       x, Wk, bk, Wv, bv, kvPart, ksPart, kvFin, ksFin);
    hipLaunchKernelGGL(reduce_kernel, dim3(20), dim3(256), 0, stream,
                       kvPart, ksPart, kvFin, ksFin);
    hipLaunchKernelGGL(pass2_kernel, dim3(GRID2), dim3(256), 0, stream,
                       x, Wq, bq, kvFin, ksFin, out);
}

// Round 16
// 53.903 us; speedup vs baseline: 1.3502x; 1.0079x over previous
//
#include <hip/hip_runtime.h>
#include <hip/hip_bf16.h>

// FAVOR+ bidirectional linear attention, N=262144, D=64, fp32 in/out.
// R15 champion (54.3us) + startup latency hoist: first x-tile global loads
// issued BEFORE weight/kv staging in both passes (T14 issue-early), hiding
// ~700cyc HBM latency under the staging+syncthreads chain.
// Pass 1 (512 blocks, (256,4)): K/V projections (bf16 MFMA) -> kv via
//   LDS-transpose MFMA accumulate -> per-block partial kv/ksum; block 0
//   zero-inits kvFin/ksFin.
// Reduce (20 blocks): coalesced slice sums -> atomicAdd into kvFin/ksFin.
// Pass 2 (512 blocks, (256,2), zero LDS/barriers in loop): swapped Q-proj
//   qp^T = mfma(Wq, x); out^T = mfma(kvA_pi, qp_repack); denom = per-lane
//   dot + 2 shfl_xor; float4 stores.

#define NPTS 262144
#define TILES (NPTS / 64)      // 4096
#define GRID1 512
#define TPB1 (TILES / GRID1)   // 8
#define GRID2 512
#define TPB2 (TILES / GRID2)   // 8
#define EPS 1e-3f

typedef __attribute__((ext_vector_type(8))) short short8;   // 8 x bf16 (4 VGPRs)
typedef __attribute__((ext_vector_type(4))) float f32x4;

__device__ __forceinline__ unsigned short f2bf(float f) {
    unsigned u = __builtin_bit_cast(unsigned, f);
    u += 0x7FFFu + ((u >> 16) & 1u);           // round-to-nearest-even
    return (unsigned short)(u >> 16);
}

__device__ __forceinline__ short8 cvt8(float4 p0, float4 p1) {
    short8 a;
    a[0] = (short)f2bf(p0.x); a[1] = (short)f2bf(p0.y); a[2] = (short)f2bf(p0.z); a[3] = (short)f2bf(p0.w);
    a[4] = (short)f2bf(p1.x); a[5] = (short)f2bf(p1.y); a[6] = (short)f2bf(p1.z); a[7] = (short)f2bf(p1.w);
    return a;
}

// barrier that drains LDS ops only (keeps global prefetch loads in flight)
__device__ __forceinline__ void lds_barrier() {
    asm volatile("s_waitcnt lgkmcnt(0)" ::: "memory");
    __builtin_amdgcn_s_barrier();
}

// coalesced stage of a 64x64 f32 matrix -> LDS bf16 [64][72]
__device__ __forceinline__ void stage_mat(const float* __restrict__ W,
                                          unsigned short (*dst)[72], int srow, int sc0) {
    const float* p = W + srow * 64 + sc0;
    float4 f0 = ((const float4*)p)[0];
    float4 f1 = ((const float4*)p)[1];
    float4 f2 = ((const float4*)p)[2];
    float4 f3 = ((const float4*)p)[3];
    float ff[16] = {f0.x, f0.y, f0.z, f0.w, f1.x, f1.y, f1.z, f1.w,
                    f2.x, f2.y, f2.z, f2.w, f3.x, f3.y, f3.z, f3.w};
    unsigned hh[8];
#pragma unroll
    for (int e = 0; e < 8; ++e)
        hh[e] = (unsigned)f2bf(ff[2 * e]) | ((unsigned)f2bf(ff[2 * e + 1]) << 16);
    uint4 u0 = {hh[0], hh[1], hh[2], hh[3]};
    uint4 u1 = {hh[4], hh[5], hh[6], hh[7]};
    *(uint4*)&dst[srow][sc0] = u0;
    *(uint4*)&dst[srow][sc0 + 8] = u1;
}

__global__ __launch_bounds__(256, 4) void pass1_kernel(
    const float* __restrict__ x,
    const float* __restrict__ Wk, const float* __restrict__ bk,
    const float* __restrict__ Wv, const float* __restrict__ bv,
    float* __restrict__ kvPart, float* __restrict__ ksPart,
    float* __restrict__ kvFin, float* __restrict__ ksFin)
{
    __shared__ unsigned short kpT[64][72];       // kp transposed [m][n]; startup: W staging
    __shared__ unsigned short vT[64][72];        // v  transposed [d][n]
    __shared__ unsigned short wkF[8][64][8];     // B-frags: [j*2+kk][lane][e]
    __shared__ unsigned short wvF[8][64][8];

    const int tid = threadIdx.x;
    const int w = tid >> 6, l = tid & 63, l15 = l & 15, lg = l >> 4;
    const int srow = tid >> 2, sc0 = (tid & 3) * 16;

    // issue first x-tile loads EARLY: latency hides under W staging below
    const int t0 = blockIdx.x * TPB1;
    const float* xbase = x + ((size_t)t0 * 64 + w * 16 + l15) * 64 + lg * 8;
    float4 c0 = *(const float4*)(xbase + 0);
    float4 c1 = *(const float4*)(xbase + 4);
    float4 c2 = *(const float4*)(xbase + 32);
    float4 c3 = *(const float4*)(xbase + 36);

    // block 0 zero-inits the atomic-reduce targets (ws is poisoned 0xAA)
    if (blockIdx.x == 0) {
        const f32x4 z4 = (f32x4){0.f, 0.f, 0.f, 0.f};
#pragma unroll
        for (int i = 0; i < 4; ++i)
            *(f32x4*)(kvFin + tid * 16 + i * 4) = z4;
        if (tid < 64) ksFin[tid] = 0.f;
    }

    // ---- startup: coalesced W staging -> LDS bf16 -> frag build ----
    {
        const float* Ws[2] = {Wk, Wv};
        unsigned short (*Fs[2])[64][8] = {wkF, wvF};
#pragma unroll
        for (int m = 0; m < 2; ++m) {
            stage_mat(Ws[m], kpT, srow, sc0);
            __syncthreads();
            // wave w builds frag j=w: F[j*2+kk][lane][e] = W[kk*32+lg*8+e][j*16+l15]
#pragma unroll
            for (int kk = 0; kk < 2; ++kk) {
                short8 t;
#pragma unroll
                for (int e = 0; e < 8; ++e)
                    t[e] = (short)kpT[kk * 32 + lg * 8 + e][w * 16 + l15];
                *(short8*)&Fs[m][w * 2 + kk][l][0] = t;
            }
            __syncthreads();
        }
    }
    float bkl[4], bvl[4];
#pragma unroll
    for (int j = 0; j < 4; ++j) { bkl[j] = bk[j * 16 + l15]; bvl[j] = bv[j * 16 + l15]; }

    f32x4 akv[4];
#pragma unroll
    for (int j = 0; j < 4; ++j) akv[j] = (f32x4){0.f, 0.f, 0.f, 0.f};
    float ks[4] = {0.f, 0.f, 0.f, 0.f};

    const int nbase = w * 16 + lg * 4;

    for (int t = 0; t < TPB1; ++t) {
        // prefetch next tile (safe re-read of current on last iter)
        const float* xn = xbase + (size_t)((t + 1 < TPB1) ? (t + 1) : t) * 4096;
        float4 n0 = *(const float4*)(xn + 0);
        float4 n1 = *(const float4*)(xn + 4);
        float4 n2 = *(const float4*)(xn + 32);
        float4 n3 = *(const float4*)(xn + 36);

        short8 a0 = cvt8(c0, c1);
        short8 a1 = cvt8(c2, c3);

#pragma unroll
        for (int j = 0; j < 4; ++j) {
            short8 bk0 = *(const short8*)&wkF[j * 2 + 0][l][0];
            short8 bk1 = *(const short8*)&wkF[j * 2 + 1][l][0];
            short8 bv0 = *(const short8*)&wvF[j * 2 + 0][l][0];
            short8 bv1 = *(const short8*)&wvF[j * 2 + 1][l][0];
            f32x4 z = (f32x4){0.f, 0.f, 0.f, 0.f};
            f32x4 ak = __builtin_amdgcn_mfma_f32_16x16x32_bf16(a0, bk0, z, 0, 0, 0);
            ak = __builtin_amdgcn_mfma_f32_16x16x32_bf16(a1, bk1, ak, 0, 0, 0);
            f32x4 av = __builtin_amdgcn_mfma_f32_16x16x32_bf16(a0, bv0, z, 0, 0, 0);
            av = __builtin_amdgcn_mfma_f32_16x16x32_bf16(a1, bv1, av, 0, 0, 0);
            unsigned short h[4], g[4];
#pragma unroll
            for (int r = 0; r < 4; ++r) {
                float kp = fmaxf(ak[r] + bkl[j], 0.f) + EPS;
                ks[j] += kp;
                h[r] = f2bf(kp);
                g[r] = f2bf(av[r] + bvl[j]);
            }
            uint2 hp = {(unsigned)h[0] | ((unsigned)h[1] << 16), (unsigned)h[2] | ((unsigned)h[3] << 16)};
            uint2 gp = {(unsigned)g[0] | ((unsigned)g[1] << 16), (unsigned)g[2] | ((unsigned)g[3] << 16)};
            *(uint2*)&kpT[j * 16 + l15][nbase] = hp;   // kpT[m][n]
            *(uint2*)&vT[j * 16 + l15][nbase] = gp;    // vT[d][n]
        }
        lds_barrier();
        // kv[m][d] += sum_n kp[n][m] * v[n][d]; wave w owns m in [w*16, w*16+16)
        short8 ka0 = *(const short8*)&kpT[w * 16 + l15][lg * 8];
        short8 ka1 = *(const short8*)&kpT[w * 16 + l15][32 + lg * 8];
#pragma unroll
        for (int j = 0; j < 4; ++j) {
            short8 vb0 = *(const short8*)&vT[j * 16 + l15][lg * 8];
            short8 vb1 = *(const short8*)&vT[j * 16 + l15][32 + lg * 8];
            akv[j] = __builtin_amdgcn_mfma_f32_16x16x32_bf16(ka0, vb0, akv[j], 0, 0, 0);
            akv[j] = __builtin_amdgcn_mfma_f32_16x16x32_bf16(ka1, vb1, akv[j], 0, 0, 0);
        }
        lds_barrier();
        c0 = n0; c1 = n1; c2 = n2; c3 = n3;
    }

    // per-block partial stores (plain, coalesced)
    float* kvs = kvPart + (size_t)blockIdx.x * 4096;
#pragma unroll
    for (int j = 0; j < 4; ++j)
#pragma unroll
        for (int r = 0; r < 4; ++r)
            kvs[(size_t)(w * 16 + lg * 4 + r) * 64 + j * 16 + l15] = akv[j][r];
#pragma unroll
    for (int j = 0; j < 4; ++j) {
        float s = ks[j];
        s += __shfl_xor(s, 16, 64);
        s += __shfl_xor(s, 32, 64);
        if (lg == 0) ksPart[(size_t)blockIdx.x * 256 + w * 64 + j * 16 + l15] = s;
    }
}

// 20 blocks: b<16 -> sum kvPart rows b*32..b*32+31 (coalesced) -> atomicAdd
//            into kvFin; b>=16 -> sum ksPart rows (b-16)*128..+127 -> ksFin
__global__ __launch_bounds__(256, 4) void reduce_kernel(
    const float* __restrict__ kvPart, const float* __restrict__ ksPart,
    float* __restrict__ kvFin, float* __restrict__ ksFin)
{
    const int b = blockIdx.x, t = threadIdx.x;
    if (b < 16) {
        f32x4 acc[4];
#pragma unroll
        for (int si = 0; si < 4; ++si) acc[si] = (f32x4){0.f, 0.f, 0.f, 0.f};
        const float* base = kvPart + (size_t)b * 32 * 4096;
#pragma unroll 4
        for (int r = 0; r < 32; ++r)
#pragma unroll
            for (int si = 0; si < 4; ++si)
                acc[si] += *(const f32x4*)(base + (size_t)r * 4096 + si * 1024 + t * 4);
#pragma unroll
        for (int si = 0; si < 4; ++si)
#pragma unroll
            for (int e = 0; e < 4; ++e)
                unsafeAtomicAdd(&kvFin[si * 1024 + t * 4 + e], acc[si][e]);
    } else {
        const int i = b - 16;
        float acc = 0.f;
        const float* p = ksPart + (size_t)i * 128 * 256 + t;
#pragma unroll 8
        for (int r = 0; r < 128; ++r) acc += p[(size_t)r * 256];
        unsafeAtomicAdd(&ksFin[t & 63], acc);
    }
}

__global__ __launch_bounds__(256, 2) void pass2_kernel(
    const float* __restrict__ x, const float* __restrict__ Wq, const float* __restrict__ bq,
    const float* __restrict__ kvFin, const float* __restrict__ ksFin,
    float* __restrict__ out)
{
    __shared__ unsigned short stageS[64][72];   // startup staging (Wq, then kv)
    __shared__ unsigned short wqF[8][64][8];    // Wq frags (A-role in swapped proj)

    const int tid = threadIdx.x;
    const int w = tid >> 6, l = tid & 63, l15 = l & 15, lg = l >> 4;
    const int srow = tid >> 2, sc0 = (tid & 3) * 16;

    // issue first x-tile loads EARLY: latency hides under Wq/kv staging below
    const int t0 = blockIdx.x * TPB2;
    const float* xbase = x + ((size_t)t0 * 64 + w * 16 + l15) * 64 + lg * 8;
    float4 c0 = *(const float4*)(xbase + 0);
    float4 c1 = *(const float4*)(xbase + 4);
    float4 c2 = *(const float4*)(xbase + 32);
    float4 c3 = *(const float4*)(xbase + 36);

    stage_mat(Wq, stageS, srow, sc0);
    __syncthreads();
    {
#pragma unroll
        for (int kk = 0; kk < 2; ++kk) {
            short8 t;
#pragma unroll
            for (int e = 0; e < 8; ++e)
                t[e] = (short)stageS[kk * 32 + lg * 8 + e][w * 16 + l15];
            *(short8*)&wqF[w * 2 + kk][l][0] = t;
        }
    }
    __syncthreads();
    stage_mat(kvFin, stageS, srow, sc0);
    __syncthreads();
    // kv A'-frags with permuted contraction pi(lg,e,kk) = (kk*2+(e>>2))*16 + lg*4 + (e&3)
    short8 kvA[4][2];
#pragma unroll
    for (int dj = 0; dj < 4; ++dj)
#pragma unroll
        for (int kk = 0; kk < 2; ++kk) {
            short8 t;
#pragma unroll
            for (int e = 0; e < 8; ++e) {
                int m = (kk * 2 + (e >> 2)) * 16 + lg * 4 + (e & 3);
                t[e] = (short)stageS[m][dj * 16 + l15];
            }
            kvA[dj][kk] = t;
        }
    // per-lane bias / ksum for m = jm*16 + lg*4 + r
    float bql2[4][4], ksl2[4][4];
#pragma unroll
    for (int jm = 0; jm < 4; ++jm)
#pragma unroll
        for (int r = 0; r < 4; ++r) {
            bql2[jm][r] = bq[jm * 16 + lg * 4 + r];
            ksl2[jm][r] = ksFin[jm * 16 + lg * 4 + r];
        }

    for (int t = 0; t < TPB2; ++t) {
        const float* xn = xbase + (size_t)((t + 1 < TPB2) ? (t + 1) : t) * 4096;
        float4 n0 = *(const float4*)(xn + 0);
        float4 n1 = *(const float4*)(xn + 4);
        float4 n2 = *(const float4*)(xn + 32);
        float4 n3 = *(const float4*)(xn + 36);

        short8 a0 = cvt8(c0, c1);
        short8 a1 = cvt8(c2, c3);

        // swapped Q projection: lane holds qp[n=w*16+l15][m=jm*16+lg*4+r]
        const f32x4 z = (f32x4){0.f, 0.f, 0.f, 0.f};
        float dp = 0.f;
        short8 qb0, qb1;
#pragma unroll
        for (int jm = 0; jm < 4; ++jm) {
            short8 wq0 = *(const short8*)&wqF[jm * 2 + 0][l][0];
            short8 wq1 = *(const short8*)&wqF[jm * 2 + 1][l][0];
            f32x4 aq = __builtin_amdgcn_mfma_f32_16x16x32_bf16(wq0, a0, z, 0, 0, 0);
            aq = __builtin_amdgcn_mfma_f32_16x16x32_bf16(wq1, a1, aq, 0, 0, 0);
#pragma unroll
            for (int r = 0; r < 4; ++r) {
                float qv = fmaxf(aq[r] + bql2[jm][r], 0.f) + EPS;
                dp += qv * ksl2[jm][r];
                unsigned short h = f2bf(qv);
                if (jm < 2) qb0[(jm & 1) * 4 + r] = (short)h;
                else        qb1[(jm & 1) * 4 + r] = (short)h;
            }
        }
        dp += __shfl_xor(dp, 16, 64);
        dp += __shfl_xor(dp, 32, 64);
        const float inv = __builtin_amdgcn_rcpf(dp);

        const size_t nrow = (size_t)(t0 + t) * 64 + w * 16 + l15;
#pragma unroll
        for (int dj = 0; dj < 4; ++dj) {
            f32x4 nm = __builtin_amdgcn_mfma_f32_16x16x32_bf16(kvA[dj][0], qb0, z, 0, 0, 0);
            nm = __builtin_amdgcn_mfma_f32_16x16x32_bf16(kvA[dj][1], qb1, nm, 0, 0, 0);
            f32x4 o4 = {nm[0] * inv, nm[1] * inv, nm[2] * inv, nm[3] * inv};
            *(f32x4*)(out + nrow * 64 + dj * 16 + lg * 4) = o4;
        }
        c0 = n0; c1 = n1; c2 = n2; c3 = n3;
    }
}

extern "C" void kernel_launch(void* const* d_in, const int* in_sizes, int n_in,
                              void* d_out, int out_size, void* d_ws, size_t ws_size,
                              hipStream_t stream)
{
    const float* x  = (const float*)d_in[0];
    const float* Wq = (const float*)d_in[1];
    const float* bq = (const float*)d_in[2];
    const float* Wk = (const float*)d_in[3];
    const float* bk = (const float*)d_in[4];
    const float* Wv = (const float*)d_in[5];
    const float* bv = (const float*)d_in[6];
    float* out = (float*)d_out;

    float* kvPart = (float*)d_ws;                              // [512][4096] f32
    float* ksPart = kvPart + (size_t)GRID1 * 4096;             // [512][256] f32
    float* kvFin  = ksPart + (size_t)GRID1 * 256;              // [4096] f32
    float* ksFin  = kvFin + 4096;                              // [64] f32

    hipLaunchKernelGGL(pass1_kernel, dim3(GRID1), dim3(256), 0, stream,
                       x, Wk, bk, Wv, bv, kvPart, ksPart, kvFin, ksFin);
    hipLaunchKernelGGL(reduce_kernel, dim3(20), dim3(256), 0, stream,
                       kvPart, ksPart, kvFin, ksFin);
    hipLaunchKernelGGL(pass2_kernel, dim3(GRID2), dim3(256), 0, stream,
                       x, Wq, bq, kvFin, ksFin, out);
}